// Round 15
// baseline (510.529 us; speedup 1.0000x reference)
//
#include <hip/hip_runtime.h>
#include <hip/hip_bf16.h>
#include <hip/hip_cooperative_groups.h>

namespace cg = cooperative_groups;

#define N_NODES 50000
#define N_EDGES 800000
#define N_RELS 65
#define DIM 64
#define N_GRAPHS 512

#define SORT_BLOCKS 1024
#define CHUNK ((N_EDGES + SORT_BLOCKS - 1) / SORT_BLOCKS)  // 782

#define SCAN_BLK 512
#define NSCAN_BLKS ((N_NODES + SCAN_BLK - 1) / SCAN_BLK)   // 98

#define MSG_BLOCKS 1024
#define NWAVES (MSG_BLOCKS * 4)

typedef __attribute__((ext_vector_type(8))) short short8;
typedef __attribute__((ext_vector_type(4))) float f32x4;

// ================= prep 1: vectorized h conversion + zero counters =================

__global__ void conv_h_zero_kernel(const float* __restrict__ x, __hip_bfloat16* __restrict__ y,
                                   int* __restrict__ cnt_d, int* __restrict__ cnt_g) {
    int i = blockIdx.x * 256 + threadIdx.x;
    if (i < (N_NODES * DIM) / 4) {
        float4 v = *(const float4*)(x + (size_t)i * 4);
        unsigned short us[4];
        us[0] = __hip_bfloat16_raw(__float2bfloat16(v.x)).x;
        us[1] = __hip_bfloat16_raw(__float2bfloat16(v.y)).x;
        us[2] = __hip_bfloat16_raw(__float2bfloat16(v.z)).x;
        us[3] = __hip_bfloat16_raw(__float2bfloat16(v.w)).x;
        *(ushort4*)(y + (size_t)i * 4) = *(const ushort4*)us;
    }
    if (i < N_NODES) cnt_d[i] = 0;
    if (i < N_GRAPHS) cnt_g[i] = 0;
}

// ================= prep 2: rel-hist (transposed out) + graph counts + W conversion =================

__global__ __launch_bounds__(256) void hist_all_kernel(
    const int* __restrict__ et, const int* __restrict__ gid,
    int* __restrict__ blk_hist, int* __restrict__ cnt_g,
    const float* __restrict__ W1, const float* __restrict__ W2,
    const float* __restrict__ W3,
    __hip_bfloat16* __restrict__ Wt1, __hip_bfloat16* __restrict__ Wt2,
    __hip_bfloat16* __restrict__ Wt3) {
    __shared__ int lh[N_RELS];
    int t = threadIdx.x, b = blockIdx.x;
    int gtid = b * 256 + t;
    if (t < N_RELS) lh[t] = 0;
    __syncthreads();
    int lo = b * CHUNK;
    int hi = lo + CHUNK; if (hi > N_EDGES) hi = N_EDGES;
    for (int i = lo + t; i < hi; i += 256)
        atomicAdd(&lh[et[i]], 1);
    for (int i = gtid; i < N_NODES; i += SORT_BLOCKS * 256)
        atomicAdd(&cnt_g[gid[i]], 1);
    const int WN = N_RELS * DIM * DIM;
    for (int i = gtid; i < 3 * WN; i += SORT_BLOCKS * 256) {
        int which = i / WN, j = i - which * WN;
        const float* W = (which == 0) ? W1 : (which == 1) ? W2 : W3;
        __hip_bfloat16* Wt = (which == 0) ? Wt1 : (which == 1) ? Wt2 : Wt3;
        int r = j >> 12, rest = j & 4095;
        int nn = rest >> 6, k = rest & 63;
        Wt[(size_t)r * 4096 + nn * 64 + k] =
            __float2bfloat16(W[(size_t)r * 4096 + k * 64 + nn]);
    }
    __syncthreads();
    if (t < N_RELS) blk_hist[t * SORT_BLOCKS + b] = lh[t];
}

// ================= prep 3: per-relation scan (coalesced, transposed layout) =================

__global__ __launch_bounds__(1024) void relwave2_kernel(const int* __restrict__ blk_hist,
                                                        int* __restrict__ blk_off,
                                                        int* __restrict__ rel_ptr,
                                                        int* __restrict__ tile_base) {
    __shared__ int tot[N_RELS];
    int t = threadIdx.x;
    int w = t >> 6, lane = t & 63;
    for (int r = w; r < N_RELS; r += 16) {
        int run = 0;
        for (int c = 0; c < SORT_BLOCKS; c += 64) {
            int b = c + lane;
            int v = blk_hist[r * SORT_BLOCKS + b];
            int x = v;
            #pragma unroll
            for (int off = 1; off < 64; off <<= 1) {
                int y = __shfl_up(x, off);
                if (lane >= off) x += y;
            }
            blk_off[r * SORT_BLOCKS + b] = run + x - v;
            run += __shfl(x, 63);
        }
        if (lane == 0) tot[r] = run;
    }
    __syncthreads();
    if (t == 0) {
        int s = 0, tt = 0;
        for (int q = 0; q < N_RELS; ++q) {
            rel_ptr[q] = s; s += tot[q];
            tile_base[q] = tt; tt += (tot[q] + 15) >> 4;
        }
        rel_ptr[N_RELS] = N_EDGES;
        tile_base[N_RELS] = tt;
    }
}

// ================= prep 4: scatter + rank, 4-edge batched for atomic MLP =================
// Phases per thread: load 4 edges -> 4 LDS atomics -> 4 INDEPENDENT global
// atomics (issued back-to-back, latencies overlap) -> 4 packed u64 stores.

__global__ __launch_bounds__(256) void scatter2_kernel(
    const int* __restrict__ et, const int* __restrict__ src,
    const int* __restrict__ dst, const int* __restrict__ blk_off,
    const int* __restrict__ rel_ptr,
    unsigned long long* __restrict__ epk, int* __restrict__ cnt_d) {
    __shared__ int cur[N_RELS];
    int t = threadIdx.x, b = blockIdx.x;
    if (t < N_RELS) cur[t] = blk_off[t * SORT_BLOCKS + b] + rel_ptr[t];
    __syncthreads();
    int lo = b * CHUNK;
    int hi = lo + CHUNK; if (hi > N_EDGES) hi = N_EDGES;

    bool val[4]; int rr[4], dd[4]; unsigned ss[4];
    #pragma unroll
    for (int k = 0; k < 4; ++k) {
        int i = lo + t + k * 256;
        val[k] = (i < hi);
        int ic = val[k] ? i : lo;
        rr[k] = et[ic]; dd[k] = dst[ic]; ss[k] = (unsigned)src[ic];
    }
    int p[4];
    #pragma unroll
    for (int k = 0; k < 4; ++k)
        if (val[k]) p[k] = atomicAdd(&cur[rr[k]], 1);
    int rk[4];
    #pragma unroll
    for (int k = 0; k < 4; ++k)
        if (val[k]) rk[k] = atomicAdd(&cnt_d[dd[k]], 1);
    #pragma unroll
    for (int k = 0; k < 4; ++k)
        if (val[k]) {
            unsigned lo32 = ss[k] | ((unsigned)dd[k] << 16);
            epk[p[k]] = (unsigned long long)lo32 |
                        ((unsigned long long)(unsigned)rk[k] << 32);
        }
}

// ================= prep 5: fused CSR scan + graph segments + unpack (cooperative) =================
// Phases: A scanblk | B chunk-base + gid scan | C scanadd | D unpack.
// Trivial register/LDS pressure; grid <= 256 (1 block/CU) -> co-resident.

struct ScanParams {
    int *cnt_d, *row_ptr, *blk_tot, *blk_base;
    const int* cnt_g; int* g_ptr;
    const unsigned long long* epk;
    int *src_s, *dpos;
};

__global__ __launch_bounds__(SCAN_BLK, 2) void scanfuse_kernel(ScanParams P) {
    cg::grid_group grid = cg::this_grid();
    __shared__ int tmp[SCAN_BLK];
    int t = threadIdx.x, b = blockIdx.x;
    int gtid = b * SCAN_BLK + t;
    int nthreads = gridDim.x * SCAN_BLK;

    // A: per-chunk exclusive scan of cnt_d
    if (b < NSCAN_BLKS) {
        int i = b * SCAN_BLK + t;
        int v = (i < N_NODES) ? P.cnt_d[i] : 0;
        tmp[t] = v;
        __syncthreads();
        for (int off = 1; off < SCAN_BLK; off <<= 1) {
            int add = (t >= off) ? tmp[t - off] : 0;
            __syncthreads();
            tmp[t] += add;
            __syncthreads();
        }
        if (i < N_NODES) P.row_ptr[i] = tmp[t] - v;
        if (t == SCAN_BLK - 1) P.blk_tot[b] = tmp[t];
    }
    grid.sync();

    // B: serial chunk-base scan (block 0) + graph-segment scan (block 1, wave 0)
    if (b == 0 && t == 0) {
        int run = 0;
        for (int c = 0; c < NSCAN_BLKS; ++c) { P.blk_base[c] = run; run += P.blk_tot[c]; }
    }
    if (b == 1 && (t >> 6) == 0) {
        int lane = t & 63;
        int run = 0;
        for (int c = 0; c < N_GRAPHS; c += 64) {
            int v = P.cnt_g[c + lane];
            int x = v;
            #pragma unroll
            for (int off = 1; off < 64; off <<= 1) {
                int y = __shfl_up(x, off);
                if (lane >= off) x += y;
            }
            P.g_ptr[c + lane] = run + x - v;
            run += __shfl(x, 63);
        }
    }
    grid.sync();

    // C: add chunk bases
    for (int i = gtid; i < N_NODES; i += nthreads)
        P.row_ptr[i] += P.blk_base[i >> 9];   // SCAN_BLK == 512
    grid.sync();

    // D: unpack epk -> src_s, dpos (sequential read, L2-resident row_ptr gather)
    for (int i = gtid; i < N_EDGES; i += nthreads) {
        unsigned long long e = P.epk[i];
        int s = (int)(e & 0xFFFFu);
        int d = (int)((e >> 16) & 0xFFFFu);
        int rank = (int)(e >> 32);
        P.src_s[i] = s;
        P.dpos[i] = rank + P.row_ptr[d];
    }
}

// ================= phase 1: MFMA message kernel (depth-2 gather pipeline) =================

__global__ __launch_bounds__(256) void msg_mfma_kernel(
    const __hip_bfloat16* __restrict__ hb, const __hip_bfloat16* __restrict__ Wt,
    const int* __restrict__ rel_ptr, const int* __restrict__ tile_base,
    const int* __restrict__ src_s, const int* __restrict__ dpos,
    __hip_bfloat16* __restrict__ msg) {
    __shared__ __align__(16) unsigned short stA[4][16 * 72];
    __shared__ __align__(16) float stC[4][16 * 68];

    int t = threadIdx.x;
    int w = t >> 6, lane = t & 63;
    int quad = lane >> 4, m16 = lane & 15;
    int wave = blockIdx.x * 4 + w;

    int ntiles = tile_base[N_RELS];
    int tpw = (ntiles + NWAVES - 1) / NWAVES;
    int T = wave * tpw;
    int T1 = T + tpw; if (T1 > ntiles) T1 = ntiles;
    if (T >= T1) return;

    unsigned short* sa = &stA[w][0];
    float* sc = &stC[w][0];
    int r0l = lane >> 3;

    int r = 0;
    while (T >= tile_base[r + 1]) ++r;

    while (T < T1) {
        int chunk_end = tile_base[r + 1]; if (chunk_end > T1) chunk_end = T1;
        int e_base = rel_ptr[r], t_base = tile_base[r];
        int seg_end = rel_ptr[r + 1];

        const __hip_bfloat16* Wr = Wt + (size_t)r * (DIM * DIM);
        short8 bf00 = *(const short8*)(Wr + (0 * 16 + m16) * DIM + quad * 8);
        short8 bf01 = *(const short8*)(Wr + (1 * 16 + m16) * DIM + quad * 8);
        short8 bf02 = *(const short8*)(Wr + (2 * 16 + m16) * DIM + quad * 8);
        short8 bf03 = *(const short8*)(Wr + (3 * 16 + m16) * DIM + quad * 8);
        short8 bf10 = *(const short8*)(Wr + (0 * 16 + m16) * DIM + 32 + quad * 8);
        short8 bf11 = *(const short8*)(Wr + (1 * 16 + m16) * DIM + 32 + quad * 8);
        short8 bf12 = *(const short8*)(Wr + (2 * 16 + m16) * DIM + 32 + quad * 8);
        short8 bf13 = *(const short8*)(Wr + (3 * 16 + m16) * DIM + 32 + quad * 8);

        auto loadidx = [&](int TT, int& sv, int& dp) {
            int TC = TT < chunk_end ? TT : chunk_end - 1;
            int i = e_base + (TC - t_base) * 16 + lane;
            if (i >= N_EDGES) i = N_EDGES - 1;
            sv = src_s[i]; dp = dpos[i];
        };
        auto gather = [&](int sv, uint4& g0, uint4& g1) {
            int s0 = __shfl(sv, r0l);
            int s1 = __shfl(sv, r0l + 8);
            g0 = *(const uint4*)(hb + (size_t)s0 * DIM + (lane & 7) * 8);
            g1 = *(const uint4*)(hb + (size_t)s1 * DIM + (lane & 7) * 8);
        };

        int sv0, dp0, sv1, dp1, sv2, dp2, sv3, dp3;
        uint4 gc0, gc1, gn0, gn1;
        loadidx(T,     sv0, dp0);
        loadidx(T + 1, sv1, dp1);
        loadidx(T + 2, sv2, dp2);
        gather(sv0, gc0, gc1);
        gather(sv1, gn0, gn1);

        for (; T < chunk_end; ++T) {
            int e0 = e_base + (T - t_base) * 16;
            int rows = seg_end - e0; if (rows > 16) rows = 16;

            uint4 gnn0, gnn1;
            gather(sv2, gnn0, gnn1);
            loadidx(T + 3, sv3, dp3);

            *(uint4*)&sa[r0l * 72 + (lane & 7) * 8] = gc0;
            *(uint4*)&sa[(r0l + 8) * 72 + (lane & 7) * 8] = gc1;

            short8 a0 = *(const short8*)&sa[m16 * 72 + quad * 8];
            short8 a1 = *(const short8*)&sa[m16 * 72 + 32 + quad * 8];

            f32x4 c0 = {0.f, 0.f, 0.f, 0.f}, c1 = c0, c2 = c0, c3 = c0;
            c0 = __builtin_amdgcn_mfma_f32_16x16x32_bf16(a0, bf00, c0, 0, 0, 0);
            c1 = __builtin_amdgcn_mfma_f32_16x16x32_bf16(a0, bf01, c1, 0, 0, 0);
            c2 = __builtin_amdgcn_mfma_f32_16x16x32_bf16(a0, bf02, c2, 0, 0, 0);
            c3 = __builtin_amdgcn_mfma_f32_16x16x32_bf16(a0, bf03, c3, 0, 0, 0);
            c0 = __builtin_amdgcn_mfma_f32_16x16x32_bf16(a1, bf10, c0, 0, 0, 0);
            c1 = __builtin_amdgcn_mfma_f32_16x16x32_bf16(a1, bf11, c1, 0, 0, 0);
            c2 = __builtin_amdgcn_mfma_f32_16x16x32_bf16(a1, bf12, c2, 0, 0, 0);
            c3 = __builtin_amdgcn_mfma_f32_16x16x32_bf16(a1, bf13, c3, 0, 0, 0);

            #pragma unroll
            for (int reg = 0; reg < 4; ++reg) {
                int rr2 = (quad * 4 + reg) * 68 + m16;
                sc[rr2 +  0] = c0[reg];
                sc[rr2 + 16] = c1[reg];
                sc[rr2 + 32] = c2[reg];
                sc[rr2 + 48] = c3[reg];
            }

            int orow = lane >> 2;
            if (orow < rows) {
                int c0i = (lane & 3) * 16;
                float vs[16];
                *(f32x4*)&vs[0]  = *(const f32x4*)&sc[orow * 68 + c0i + 0];
                *(f32x4*)&vs[4]  = *(const f32x4*)&sc[orow * 68 + c0i + 4];
                *(f32x4*)&vs[8]  = *(const f32x4*)&sc[orow * 68 + c0i + 8];
                *(f32x4*)&vs[12] = *(const f32x4*)&sc[orow * 68 + c0i + 12];
                unsigned short us[16];
                #pragma unroll
                for (int i = 0; i < 16; ++i)
                    us[i] = __hip_bfloat16_raw(__float2bfloat16(vs[i])).x;
                int dprow = __shfl(dp0, orow);
                __hip_bfloat16* dstp = msg + (size_t)dprow * DIM + c0i;
                *(uint4*)dstp = *(const uint4*)&us[0];
                *(uint4*)(dstp + 8) = *(const uint4*)&us[8];
            }

            gc0 = gn0; gc1 = gn1; gn0 = gnn0; gn1 = gnn1;
            sv0 = sv1; dp0 = dp1; sv1 = sv2; dp1 = dp2; sv2 = sv3; dp2 = dp3;
        }
        ++r;
        while (T < T1 && T >= tile_base[r + 1]) ++r;
    }
}

// ================= phase 2: vectorized pull-aggregate + bias + ReLU =================

__global__ __launch_bounds__(256) void agg_kernel(
    const __hip_bfloat16* __restrict__ msg, const int* __restrict__ row_ptr,
    const int* __restrict__ cnt_d, const float* __restrict__ b,
    __hip_bfloat16* __restrict__ hout) {
    int wave = blockIdx.x * 4 + (threadIdx.x >> 6);
    int lane = threadIdx.x & 63;
    if (wave >= N_NODES) return;
    int j0 = row_ptr[wave];
    int n  = cnt_d[wave];
    int rgrp = lane >> 3, dgrp = lane & 7;

    float a[8] = {0.f, 0.f, 0.f, 0.f, 0.f, 0.f, 0.f, 0.f};
    for (int jj = 0; jj < n; jj += 8) {
        int row = jj + rgrp;
        if (row < n) {
            uint4 d = *(const uint4*)(msg + (size_t)(j0 + row) * DIM + dgrp * 8);
            a[0] += __uint_as_float(d.x << 16);
            a[1] += __uint_as_float(d.x & 0xffff0000u);
            a[2] += __uint_as_float(d.y << 16);
            a[3] += __uint_as_float(d.y & 0xffff0000u);
            a[4] += __uint_as_float(d.z << 16);
            a[5] += __uint_as_float(d.z & 0xffff0000u);
            a[6] += __uint_as_float(d.w << 16);
            a[7] += __uint_as_float(d.w & 0xffff0000u);
        }
    }
    #pragma unroll
    for (int i = 0; i < 8; ++i) {
        a[i] += __shfl_xor(a[i], 8);
        a[i] += __shfl_xor(a[i], 16);
        a[i] += __shfl_xor(a[i], 32);
    }
    if (rgrp == 0) {
        unsigned short us[8];
        #pragma unroll
        for (int i = 0; i < 8; ++i) {
            float v = a[i] + b[dgrp * 8 + i];
            us[i] = __hip_bfloat16_raw(__float2bfloat16(v > 0.f ? v : 0.f)).x;
        }
        *(uint4*)(hout + (size_t)wave * DIM + dgrp * 8) = *(const uint4*)us;
    }
}

// ================= fused pool + FC x3 + prediction head =================

__global__ __launch_bounds__(256) void poolfc_kernel(
    const __hip_bfloat16* __restrict__ h, const int* __restrict__ g_ptr,
    const int* __restrict__ cnt_g,
    const float* __restrict__ W1, const float* __restrict__ b1,
    const float* __restrict__ W2, const float* __restrict__ b2,
    const float* __restrict__ W3, const float* __restrict__ b3,
    const float* __restrict__ pW, const float* __restrict__ pb,
    float* __restrict__ out) {
    int wave = blockIdx.x * 4 + (threadIdx.x >> 6);
    int lane = threadIdx.x & 63;
    if (wave >= N_GRAPHS) return;
    int j0 = g_ptr[wave];
    int n  = cnt_g[wave];
    int rgrp = lane >> 3, dgrp = lane & 7;

    float a[8] = {0.f, 0.f, 0.f, 0.f, 0.f, 0.f, 0.f, 0.f};
    for (int jj = 0; jj < n; jj += 8) {
        int row = jj + rgrp;
        if (row < n) {
            uint4 d = *(const uint4*)(h + (size_t)(j0 + row) * DIM + dgrp * 8);
            a[0] += __uint_as_float(d.x << 16);
            a[1] += __uint_as_float(d.x & 0xffff0000u);
            a[2] += __uint_as_float(d.y << 16);
            a[3] += __uint_as_float(d.y & 0xffff0000u);
            a[4] += __uint_as_float(d.z << 16);
            a[5] += __uint_as_float(d.z & 0xffff0000u);
            a[6] += __uint_as_float(d.w << 16);
            a[7] += __uint_as_float(d.w & 0xffff0000u);
        }
    }
    #pragma unroll
    for (int i = 0; i < 8; ++i) {
        a[i] += __shfl_xor(a[i], 8);
        a[i] += __shfl_xor(a[i], 16);
        a[i] += __shfl_xor(a[i], 32);
    }
    float v;
    {
        float acc = b1[lane];
        #pragma unroll
        for (int o = 0; o < 8; ++o)
            #pragma unroll
            for (int q = 0; q < 8; ++q)
                acc += __shfl(a[o], q) * W1[(q * 8 + o) * DIM + lane];
        v = acc > 0.f ? acc : 0.f;
    }
    {
        float acc = b2[lane];
        #pragma unroll
        for (int d = 0; d < DIM; ++d)
            acc += __shfl(v, d) * W2[d * DIM + lane];
        v = acc > 0.f ? acc : 0.f;
    }
    {
        float acc = b3[lane];
        #pragma unroll
        for (int d = 0; d < DIM; ++d)
            acc += __shfl(v, d) * W3[d * DIM + lane];
        v = acc > 0.f ? acc : 0.f;
    }
    float p0 = v * pW[lane * 2 + 0];
    float p1 = v * pW[lane * 2 + 1];
    #pragma unroll
    for (int off = 32; off > 0; off >>= 1) {
        p0 += __shfl_down(p0, off);
        p1 += __shfl_down(p1, off);
    }
    if (lane == 0) {
        out[wave * 2 + 0] = p0 + pb[0];
        out[wave * 2 + 1] = p1 + pb[1];
    }
}

// ================= launch =================

extern "C" void kernel_launch(void* const* d_in, const int* in_sizes, int n_in,
                              void* d_out, int out_size, void* d_ws, size_t ws_size,
                              hipStream_t stream) {
    const float* node_feats = (const float*)d_in[0];
    const int*   etypes     = (const int*)d_in[1];
    const int*   src        = (const int*)d_in[2];
    const int*   dst        = (const int*)d_in[3];
    const int*   graph_ids  = (const int*)d_in[4];
    const float* W1 = (const float*)d_in[5];
    const float* b1 = (const float*)d_in[6];
    const float* W2 = (const float*)d_in[7];
    const float* b2 = (const float*)d_in[8];
    const float* W3 = (const float*)d_in[9];
    const float* b3 = (const float*)d_in[10];
    const float* fcW1 = (const float*)d_in[11];
    const float* fcb1 = (const float*)d_in[12];
    const float* fcW2 = (const float*)d_in[13];
    const float* fcb2 = (const float*)d_in[14];
    const float* fcW3 = (const float*)d_in[15];
    const float* fcb3 = (const float*)d_in[16];
    const float* pW = (const float*)d_in[17];
    const float* pb = (const float*)d_in[18];
    float* out = (float*)d_out;

    // workspace carve-up (256B aligned)
    char* p = (char*)d_ws;
    auto alloc = [&](size_t bytes) -> void* {
        void* r = (void*)p;
        p += (bytes + 255) & ~(size_t)255;
        return r;
    };
    int* blk_hist  = (int*)alloc((size_t)SORT_BLOCKS * N_RELS * sizeof(int));
    int* blk_off   = (int*)alloc((size_t)SORT_BLOCKS * N_RELS * sizeof(int));
    int* rel_ptr   = (int*)alloc((N_RELS + 1) * sizeof(int));
    int* tile_base = (int*)alloc((N_RELS + 1) * sizeof(int));
    unsigned long long* epk = (unsigned long long*)alloc((size_t)N_EDGES * sizeof(unsigned long long));
    int* src_s     = (int*)alloc((size_t)N_EDGES * sizeof(int));
    int* dpos      = (int*)alloc((size_t)N_EDGES * sizeof(int));
    int* cnt_d     = (int*)alloc((size_t)N_NODES * sizeof(int));
    int* row_ptr   = (int*)alloc((size_t)N_NODES * sizeof(int));
    int* blk_tot   = (int*)alloc(NSCAN_BLKS * sizeof(int));
    int* blk_base  = (int*)alloc(NSCAN_BLKS * sizeof(int));
    int* cnt_g     = (int*)alloc(N_GRAPHS * sizeof(int));
    int* g_ptr     = (int*)alloc(N_GRAPHS * sizeof(int));
    __hip_bfloat16* hb0 = (__hip_bfloat16*)alloc((size_t)N_NODES * DIM * sizeof(__hip_bfloat16));
    __hip_bfloat16* hb1 = (__hip_bfloat16*)alloc((size_t)N_NODES * DIM * sizeof(__hip_bfloat16));
    __hip_bfloat16* Wt1 = (__hip_bfloat16*)alloc((size_t)N_RELS * DIM * DIM * sizeof(__hip_bfloat16));
    __hip_bfloat16* Wt2 = (__hip_bfloat16*)alloc((size_t)N_RELS * DIM * DIM * sizeof(__hip_bfloat16));
    __hip_bfloat16* Wt3 = (__hip_bfloat16*)alloc((size_t)N_RELS * DIM * DIM * sizeof(__hip_bfloat16));
    __hip_bfloat16* msg = (__hip_bfloat16*)alloc((size_t)N_EDGES * DIM * sizeof(__hip_bfloat16));

    const int CBLK = (N_NODES * DIM / 4 + 255) / 256;    // 3125
    const int AGG_BLOCKS = (N_NODES + 3) / 4;            // 12500

    // ---- prep (5 dispatches) ----
    conv_h_zero_kernel<<<CBLK, 256, 0, stream>>>(node_feats, hb0, cnt_d, cnt_g);
    hist_all_kernel<<<SORT_BLOCKS, 256, 0, stream>>>(etypes, graph_ids, blk_hist, cnt_g,
                                                     W1, W2, W3, Wt1, Wt2, Wt3);
    relwave2_kernel<<<1, 1024, 0, stream>>>(blk_hist, blk_off, rel_ptr, tile_base);
    scatter2_kernel<<<SORT_BLOCKS, 256, 0, stream>>>(etypes, src, dst, blk_off, rel_ptr,
                                                     epk, cnt_d);
    {
        ScanParams SP;
        SP.cnt_d = cnt_d; SP.row_ptr = row_ptr; SP.blk_tot = blk_tot;
        SP.blk_base = blk_base; SP.cnt_g = cnt_g; SP.g_ptr = g_ptr;
        SP.epk = epk; SP.src_s = src_s; SP.dpos = dpos;
        int blkPerCU = 0;
        (void)hipOccupancyMaxActiveBlocksPerMultiprocessor(&blkPerCU,
                                                           (const void*)scanfuse_kernel,
                                                           SCAN_BLK, 0);
        if (blkPerCU < 1) blkPerCU = 1;
        int grid = blkPerCU * 256;
        if (grid > 256) grid = 256;
        if (grid < NSCAN_BLKS) grid = NSCAN_BLKS;
        void* args[] = { &SP };
        hipLaunchCooperativeKernel((const void*)scanfuse_kernel, dim3(grid),
                                   dim3(SCAN_BLK), args, 0, stream);
    }

    // ---- 3 RGCN layers (6 dispatches) ----
    msg_mfma_kernel<<<MSG_BLOCKS, 256, 0, stream>>>(hb0, Wt1, rel_ptr, tile_base,
                                                    src_s, dpos, msg);
    agg_kernel<<<AGG_BLOCKS, 256, 0, stream>>>(msg, row_ptr, cnt_d, b1, hb1);

    msg_mfma_kernel<<<MSG_BLOCKS, 256, 0, stream>>>(hb1, Wt2, rel_ptr, tile_base,
                                                    src_s, dpos, msg);
    agg_kernel<<<AGG_BLOCKS, 256, 0, stream>>>(msg, row_ptr, cnt_d, b2, hb0);

    msg_mfma_kernel<<<MSG_BLOCKS, 256, 0, stream>>>(hb0, Wt3, rel_ptr, tile_base,
                                                    src_s, dpos, msg);
    agg_kernel<<<AGG_BLOCKS, 256, 0, stream>>>(msg, row_ptr, cnt_d, b3, hb1);

    // ---- fused pool + FC head ----
    poolfc_kernel<<<(N_GRAPHS + 3) / 4, 256, 0, stream>>>(hb1, g_ptr, cnt_g,
                                                          fcW1, fcb1, fcW2, fcb2,
                                                          fcW3, fcb3, pW, pb, out);
}

// Round 16
// 392.455 us; speedup vs baseline: 1.3009x; 1.3009x over previous
//
#include <hip/hip_runtime.h>
#include <hip/hip_bf16.h>

#define N_NODES 50000
#define N_EDGES 800000
#define N_RELS 65
#define DIM 64
#define N_GRAPHS 512

#define SORT_BLOCKS 1024
#define CHUNK ((N_EDGES + SORT_BLOCKS - 1) / SORT_BLOCKS)  // 782

#define SCAN_BLK 512
#define NSCAN_BLKS ((N_NODES + SCAN_BLK - 1) / SCAN_BLK)   // 98

#define MSG_BLOCKS 1024
#define NWAVES (MSG_BLOCKS * 4)

typedef __attribute__((ext_vector_type(8))) short short8;
typedef __attribute__((ext_vector_type(4))) float f32x4;

// ================= prep 1: vectorized h conversion + zero counters =================

__global__ void conv_h_zero_kernel(const float* __restrict__ x, __hip_bfloat16* __restrict__ y,
                                   int* __restrict__ cnt_d, int* __restrict__ cnt_g) {
    int i = blockIdx.x * 256 + threadIdx.x;
    if (i < (N_NODES * DIM) / 4) {
        float4 v = *(const float4*)(x + (size_t)i * 4);
        unsigned short us[4];
        us[0] = __hip_bfloat16_raw(__float2bfloat16(v.x)).x;
        us[1] = __hip_bfloat16_raw(__float2bfloat16(v.y)).x;
        us[2] = __hip_bfloat16_raw(__float2bfloat16(v.z)).x;
        us[3] = __hip_bfloat16_raw(__float2bfloat16(v.w)).x;
        *(ushort4*)(y + (size_t)i * 4) = *(const ushort4*)us;
    }
    if (i < N_NODES) cnt_d[i] = 0;
    if (i < N_GRAPHS) cnt_g[i] = 0;
}

// ================= prep 2: rel-hist (transposed out) + graph counts + W conversion =================

__global__ __launch_bounds__(256) void hist_all_kernel(
    const int* __restrict__ et, const int* __restrict__ gid,
    int* __restrict__ blk_hist, int* __restrict__ cnt_g,
    const float* __restrict__ W1, const float* __restrict__ W2,
    const float* __restrict__ W3,
    __hip_bfloat16* __restrict__ Wt1, __hip_bfloat16* __restrict__ Wt2,
    __hip_bfloat16* __restrict__ Wt3) {
    __shared__ int lh[N_RELS];
    int t = threadIdx.x, b = blockIdx.x;
    int gtid = b * 256 + t;
    if (t < N_RELS) lh[t] = 0;
    __syncthreads();
    int lo = b * CHUNK;
    int hi = lo + CHUNK; if (hi > N_EDGES) hi = N_EDGES;
    for (int i = lo + t; i < hi; i += 256)
        atomicAdd(&lh[et[i]], 1);
    for (int i = gtid; i < N_NODES; i += SORT_BLOCKS * 256)
        atomicAdd(&cnt_g[gid[i]], 1);
    const int WN = N_RELS * DIM * DIM;
    for (int i = gtid; i < 3 * WN; i += SORT_BLOCKS * 256) {
        int which = i / WN, j = i - which * WN;
        const float* W = (which == 0) ? W1 : (which == 1) ? W2 : W3;
        __hip_bfloat16* Wt = (which == 0) ? Wt1 : (which == 1) ? Wt2 : Wt3;
        int r = j >> 12, rest = j & 4095;
        int nn = rest >> 6, k = rest & 63;
        Wt[(size_t)r * 4096 + nn * 64 + k] =
            __float2bfloat16(W[(size_t)r * 4096 + k * 64 + nn]);
    }
    __syncthreads();
    if (t < N_RELS) blk_hist[t * SORT_BLOCKS + b] = lh[t];
}

// ================= prep 3: per-relation scan (coalesced, transposed layout) =================

__global__ __launch_bounds__(1024) void relwave2_kernel(const int* __restrict__ blk_hist,
                                                        int* __restrict__ blk_off,
                                                        int* __restrict__ rel_ptr,
                                                        int* __restrict__ tile_base) {
    __shared__ int tot[N_RELS];
    int t = threadIdx.x;
    int w = t >> 6, lane = t & 63;
    for (int r = w; r < N_RELS; r += 16) {
        int run = 0;
        for (int c = 0; c < SORT_BLOCKS; c += 64) {
            int b = c + lane;
            int v = blk_hist[r * SORT_BLOCKS + b];
            int x = v;
            #pragma unroll
            for (int off = 1; off < 64; off <<= 1) {
                int y = __shfl_up(x, off);
                if (lane >= off) x += y;
            }
            blk_off[r * SORT_BLOCKS + b] = run + x - v;
            run += __shfl(x, 63);
        }
        if (lane == 0) tot[r] = run;
    }
    __syncthreads();
    if (t == 0) {
        int s = 0, tt = 0;
        for (int q = 0; q < N_RELS; ++q) {
            rel_ptr[q] = s; s += tot[q];
            tile_base[q] = tt; tt += (tot[q] + 15) >> 4;
        }
        rel_ptr[N_RELS] = N_EDGES;
        tile_base[N_RELS] = tt;
    }
}

// ================= prep 4: scatter + rank, 4-edge batched for atomic MLP =================

__global__ __launch_bounds__(256) void scatter2_kernel(
    const int* __restrict__ et, const int* __restrict__ src,
    const int* __restrict__ dst, const int* __restrict__ blk_off,
    const int* __restrict__ rel_ptr,
    unsigned long long* __restrict__ epk, int* __restrict__ cnt_d) {
    __shared__ int cur[N_RELS];
    int t = threadIdx.x, b = blockIdx.x;
    if (t < N_RELS) cur[t] = blk_off[t * SORT_BLOCKS + b] + rel_ptr[t];
    __syncthreads();
    int lo = b * CHUNK;
    int hi = lo + CHUNK; if (hi > N_EDGES) hi = N_EDGES;

    bool val[4]; int rr[4], dd[4]; unsigned ss[4];
    #pragma unroll
    for (int k = 0; k < 4; ++k) {
        int i = lo + t + k * 256;
        val[k] = (i < hi);
        int ic = val[k] ? i : lo;
        rr[k] = et[ic]; dd[k] = dst[ic]; ss[k] = (unsigned)src[ic];
    }
    int p[4];
    #pragma unroll
    for (int k = 0; k < 4; ++k)
        if (val[k]) p[k] = atomicAdd(&cur[rr[k]], 1);
    int rk[4];
    #pragma unroll
    for (int k = 0; k < 4; ++k)
        if (val[k]) rk[k] = atomicAdd(&cnt_d[dd[k]], 1);
    #pragma unroll
    for (int k = 0; k < 4; ++k)
        if (val[k]) {
            unsigned lo32 = ss[k] | ((unsigned)dd[k] << 16);
            epk[p[k]] = (unsigned long long)lo32 |
                        ((unsigned long long)(unsigned)rk[k] << 32);
        }
}

// ================= prep 5-8: dst CSR scan + graph segments + unpack =================

__global__ __launch_bounds__(SCAN_BLK) void scanblk_kernel(const int* __restrict__ cnt,
                                                           int* __restrict__ outv,
                                                           int* __restrict__ blk_tot) {
    __shared__ int tmp[SCAN_BLK];
    int t = threadIdx.x;
    int i = blockIdx.x * SCAN_BLK + t;
    int v = (i < N_NODES) ? cnt[i] : 0;
    tmp[t] = v;
    __syncthreads();
    for (int off = 1; off < SCAN_BLK; off <<= 1) {
        int add = (t >= off) ? tmp[t - off] : 0;
        __syncthreads();
        tmp[t] += add;
        __syncthreads();
    }
    if (i < N_NODES) outv[i] = tmp[t] - v;  // exclusive
    if (t == SCAN_BLK - 1) blk_tot[blockIdx.x] = tmp[t];
}

__global__ __launch_bounds__(64) void scantop_gid_kernel(
    const int* __restrict__ blk_tot, int* __restrict__ blk_base,
    const int* __restrict__ cnt_g, int* __restrict__ g_ptr) {
    int lane = threadIdx.x;
    if (blockIdx.x == 0) {
        if (lane == 0) {
            int run = 0;
            for (int b = 0; b < NSCAN_BLKS; ++b) { blk_base[b] = run; run += blk_tot[b]; }
        }
    } else {
        int run = 0;
        for (int c = 0; c < N_GRAPHS; c += 64) {
            int v = cnt_g[c + lane];
            int x = v;
            #pragma unroll
            for (int off = 1; off < 64; off <<= 1) {
                int y = __shfl_up(x, off);
                if (lane >= off) x += y;
            }
            g_ptr[c + lane] = run + x - v;
            run += __shfl(x, 63);
        }
    }
}

__global__ __launch_bounds__(SCAN_BLK) void scanadd_kernel(int* __restrict__ outv,
                                                           const int* __restrict__ blk_base) {
    int i = blockIdx.x * SCAN_BLK + threadIdx.x;
    if (i < N_NODES) outv[i] += blk_base[blockIdx.x];
}

__global__ void unpack_kernel(const unsigned long long* __restrict__ epk,
                              const int* __restrict__ row_ptr,
                              int* __restrict__ src_s, int* __restrict__ dpos) {
    int i = blockIdx.x * 256 + threadIdx.x;
    if (i < N_EDGES) {
        unsigned long long e = epk[i];
        int s = (int)(e & 0xFFFFu);
        int d = (int)((e >> 16) & 0xFFFFu);
        int rank = (int)(e >> 32);
        src_s[i] = s;
        dpos[i] = rank + row_ptr[d];
    }
}

// ================= phase 1: MFMA message kernel (depth-2 gather pipeline) =================

__global__ __launch_bounds__(256) void msg_mfma_kernel(
    const __hip_bfloat16* __restrict__ hb, const __hip_bfloat16* __restrict__ Wt,
    const int* __restrict__ rel_ptr, const int* __restrict__ tile_base,
    const int* __restrict__ src_s, const int* __restrict__ dpos,
    __hip_bfloat16* __restrict__ msg) {
    __shared__ __align__(16) unsigned short stA[4][16 * 72];
    __shared__ __align__(16) float stC[4][16 * 68];

    int t = threadIdx.x;
    int w = t >> 6, lane = t & 63;
    int quad = lane >> 4, m16 = lane & 15;
    int wave = blockIdx.x * 4 + w;

    int ntiles = tile_base[N_RELS];
    int tpw = (ntiles + NWAVES - 1) / NWAVES;
    int T = wave * tpw;
    int T1 = T + tpw; if (T1 > ntiles) T1 = ntiles;
    if (T >= T1) return;

    unsigned short* sa = &stA[w][0];
    float* sc = &stC[w][0];
    int r0l = lane >> 3;

    int r = 0;
    while (T >= tile_base[r + 1]) ++r;

    while (T < T1) {
        int chunk_end = tile_base[r + 1]; if (chunk_end > T1) chunk_end = T1;
        int e_base = rel_ptr[r], t_base = tile_base[r];
        int seg_end = rel_ptr[r + 1];

        const __hip_bfloat16* Wr = Wt + (size_t)r * (DIM * DIM);
        short8 bf00 = *(const short8*)(Wr + (0 * 16 + m16) * DIM + quad * 8);
        short8 bf01 = *(const short8*)(Wr + (1 * 16 + m16) * DIM + quad * 8);
        short8 bf02 = *(const short8*)(Wr + (2 * 16 + m16) * DIM + quad * 8);
        short8 bf03 = *(const short8*)(Wr + (3 * 16 + m16) * DIM + quad * 8);
        short8 bf10 = *(const short8*)(Wr + (0 * 16 + m16) * DIM + 32 + quad * 8);
        short8 bf11 = *(const short8*)(Wr + (1 * 16 + m16) * DIM + 32 + quad * 8);
        short8 bf12 = *(const short8*)(Wr + (2 * 16 + m16) * DIM + 32 + quad * 8);
        short8 bf13 = *(const short8*)(Wr + (3 * 16 + m16) * DIM + 32 + quad * 8);

        auto loadidx = [&](int TT, int& sv, int& dp) {
            int TC = TT < chunk_end ? TT : chunk_end - 1;
            int i = e_base + (TC - t_base) * 16 + lane;
            if (i >= N_EDGES) i = N_EDGES - 1;
            sv = src_s[i]; dp = dpos[i];
        };
        auto gather = [&](int sv, uint4& g0, uint4& g1) {
            int s0 = __shfl(sv, r0l);
            int s1 = __shfl(sv, r0l + 8);
            g0 = *(const uint4*)(hb + (size_t)s0 * DIM + (lane & 7) * 8);
            g1 = *(const uint4*)(hb + (size_t)s1 * DIM + (lane & 7) * 8);
        };

        int sv0, dp0, sv1, dp1, sv2, dp2, sv3, dp3;
        uint4 gc0, gc1, gn0, gn1;
        loadidx(T,     sv0, dp0);
        loadidx(T + 1, sv1, dp1);
        loadidx(T + 2, sv2, dp2);
        gather(sv0, gc0, gc1);
        gather(sv1, gn0, gn1);

        for (; T < chunk_end; ++T) {
            int e0 = e_base + (T - t_base) * 16;
            int rows = seg_end - e0; if (rows > 16) rows = 16;

            uint4 gnn0, gnn1;
            gather(sv2, gnn0, gnn1);
            loadidx(T + 3, sv3, dp3);

            *(uint4*)&sa[r0l * 72 + (lane & 7) * 8] = gc0;
            *(uint4*)&sa[(r0l + 8) * 72 + (lane & 7) * 8] = gc1;

            short8 a0 = *(const short8*)&sa[m16 * 72 + quad * 8];
            short8 a1 = *(const short8*)&sa[m16 * 72 + 32 + quad * 8];

            f32x4 c0 = {0.f, 0.f, 0.f, 0.f}, c1 = c0, c2 = c0, c3 = c0;
            c0 = __builtin_amdgcn_mfma_f32_16x16x32_bf16(a0, bf00, c0, 0, 0, 0);
            c1 = __builtin_amdgcn_mfma_f32_16x16x32_bf16(a0, bf01, c1, 0, 0, 0);
            c2 = __builtin_amdgcn_mfma_f32_16x16x32_bf16(a0, bf02, c2, 0, 0, 0);
            c3 = __builtin_amdgcn_mfma_f32_16x16x32_bf16(a0, bf03, c3, 0, 0, 0);
            c0 = __builtin_amdgcn_mfma_f32_16x16x32_bf16(a1, bf10, c0, 0, 0, 0);
            c1 = __builtin_amdgcn_mfma_f32_16x16x32_bf16(a1, bf11, c1, 0, 0, 0);
            c2 = __builtin_amdgcn_mfma_f32_16x16x32_bf16(a1, bf12, c2, 0, 0, 0);
            c3 = __builtin_amdgcn_mfma_f32_16x16x32_bf16(a1, bf13, c3, 0, 0, 0);

            #pragma unroll
            for (int reg = 0; reg < 4; ++reg) {
                int rr2 = (quad * 4 + reg) * 68 + m16;
                sc[rr2 +  0] = c0[reg];
                sc[rr2 + 16] = c1[reg];
                sc[rr2 + 32] = c2[reg];
                sc[rr2 + 48] = c3[reg];
            }

            int orow = lane >> 2;
            if (orow < rows) {
                int c0i = (lane & 3) * 16;
                float vs[16];
                *(f32x4*)&vs[0]  = *(const f32x4*)&sc[orow * 68 + c0i + 0];
                *(f32x4*)&vs[4]  = *(const f32x4*)&sc[orow * 68 + c0i + 4];
                *(f32x4*)&vs[8]  = *(const f32x4*)&sc[orow * 68 + c0i + 8];
                *(f32x4*)&vs[12] = *(const f32x4*)&sc[orow * 68 + c0i + 12];
                unsigned short us[16];
                #pragma unroll
                for (int i = 0; i < 16; ++i)
                    us[i] = __hip_bfloat16_raw(__float2bfloat16(vs[i])).x;
                int dprow = __shfl(dp0, orow);
                __hip_bfloat16* dstp = msg + (size_t)dprow * DIM + c0i;
                *(uint4*)dstp = *(const uint4*)&us[0];
                *(uint4*)(dstp + 8) = *(const uint4*)&us[8];
            }

            gc0 = gn0; gc1 = gn1; gn0 = gnn0; gn1 = gnn1;
            sv0 = sv1; dp0 = dp1; sv1 = sv2; dp1 = dp2; sv2 = sv3; dp2 = dp3;
        }
        ++r;
        while (T < T1 && T >= tile_base[r + 1]) ++r;
    }
}

// ================= phase 2: vectorized pull-aggregate + bias + ReLU =================

__global__ __launch_bounds__(256) void agg_kernel(
    const __hip_bfloat16* __restrict__ msg, const int* __restrict__ row_ptr,
    const int* __restrict__ cnt_d, const float* __restrict__ b,
    __hip_bfloat16* __restrict__ hout) {
    int wave = blockIdx.x * 4 + (threadIdx.x >> 6);
    int lane = threadIdx.x & 63;
    if (wave >= N_NODES) return;
    int j0 = row_ptr[wave];
    int n  = cnt_d[wave];
    int rgrp = lane >> 3, dgrp = lane & 7;

    float a[8] = {0.f, 0.f, 0.f, 0.f, 0.f, 0.f, 0.f, 0.f};
    for (int jj = 0; jj < n; jj += 8) {
        int row = jj + rgrp;
        if (row < n) {
            uint4 d = *(const uint4*)(msg + (size_t)(j0 + row) * DIM + dgrp * 8);
            a[0] += __uint_as_float(d.x << 16);
            a[1] += __uint_as_float(d.x & 0xffff0000u);
            a[2] += __uint_as_float(d.y << 16);
            a[3] += __uint_as_float(d.y & 0xffff0000u);
            a[4] += __uint_as_float(d.z << 16);
            a[5] += __uint_as_float(d.z & 0xffff0000u);
            a[6] += __uint_as_float(d.w << 16);
            a[7] += __uint_as_float(d.w & 0xffff0000u);
        }
    }
    #pragma unroll
    for (int i = 0; i < 8; ++i) {
        a[i] += __shfl_xor(a[i], 8);
        a[i] += __shfl_xor(a[i], 16);
        a[i] += __shfl_xor(a[i], 32);
    }
    if (rgrp == 0) {
        unsigned short us[8];
        #pragma unroll
        for (int i = 0; i < 8; ++i) {
            float v = a[i] + b[dgrp * 8 + i];
            us[i] = __hip_bfloat16_raw(__float2bfloat16(v > 0.f ? v : 0.f)).x;
        }
        *(uint4*)(hout + (size_t)wave * DIM + dgrp * 8) = *(const uint4*)us;
    }
}

// ================= fused pool + FC x3 + prediction head =================

__global__ __launch_bounds__(256) void poolfc_kernel(
    const __hip_bfloat16* __restrict__ h, const int* __restrict__ g_ptr,
    const int* __restrict__ cnt_g,
    const float* __restrict__ W1, const float* __restrict__ b1,
    const float* __restrict__ W2, const float* __restrict__ b2,
    const float* __restrict__ W3, const float* __restrict__ b3,
    const float* __restrict__ pW, const float* __restrict__ pb,
    float* __restrict__ out) {
    int wave = blockIdx.x * 4 + (threadIdx.x >> 6);
    int lane = threadIdx.x & 63;
    if (wave >= N_GRAPHS) return;
    int j0 = g_ptr[wave];
    int n  = cnt_g[wave];
    int rgrp = lane >> 3, dgrp = lane & 7;

    float a[8] = {0.f, 0.f, 0.f, 0.f, 0.f, 0.f, 0.f, 0.f};
    for (int jj = 0; jj < n; jj += 8) {
        int row = jj + rgrp;
        if (row < n) {
            uint4 d = *(const uint4*)(h + (size_t)(j0 + row) * DIM + dgrp * 8);
            a[0] += __uint_as_float(d.x << 16);
            a[1] += __uint_as_float(d.x & 0xffff0000u);
            a[2] += __uint_as_float(d.y << 16);
            a[3] += __uint_as_float(d.y & 0xffff0000u);
            a[4] += __uint_as_float(d.z << 16);
            a[5] += __uint_as_float(d.z & 0xffff0000u);
            a[6] += __uint_as_float(d.w << 16);
            a[7] += __uint_as_float(d.w & 0xffff0000u);
        }
    }
    #pragma unroll
    for (int i = 0; i < 8; ++i) {
        a[i] += __shfl_xor(a[i], 8);
        a[i] += __shfl_xor(a[i], 16);
        a[i] += __shfl_xor(a[i], 32);
    }
    float v;
    {
        float acc = b1[lane];
        #pragma unroll
        for (int o = 0; o < 8; ++o)
            #pragma unroll
            for (int q = 0; q < 8; ++q)
                acc += __shfl(a[o], q) * W1[(q * 8 + o) * DIM + lane];
        v = acc > 0.f ? acc : 0.f;
    }
    {
        float acc = b2[lane];
        #pragma unroll
        for (int d = 0; d < DIM; ++d)
            acc += __shfl(v, d) * W2[d * DIM + lane];
        v = acc > 0.f ? acc : 0.f;
    }
    {
        float acc = b3[lane];
        #pragma unroll
        for (int d = 0; d < DIM; ++d)
            acc += __shfl(v, d) * W3[d * DIM + lane];
        v = acc > 0.f ? acc : 0.f;
    }
    float p0 = v * pW[lane * 2 + 0];
    float p1 = v * pW[lane * 2 + 1];
    #pragma unroll
    for (int off = 32; off > 0; off >>= 1) {
        p0 += __shfl_down(p0, off);
        p1 += __shfl_down(p1, off);
    }
    if (lane == 0) {
        out[wave * 2 + 0] = p0 + pb[0];
        out[wave * 2 + 1] = p1 + pb[1];
    }
}

// ================= launch =================

extern "C" void kernel_launch(void* const* d_in, const int* in_sizes, int n_in,
                              void* d_out, int out_size, void* d_ws, size_t ws_size,
                              hipStream_t stream) {
    const float* node_feats = (const float*)d_in[0];
    const int*   etypes     = (const int*)d_in[1];
    const int*   src        = (const int*)d_in[2];
    const int*   dst        = (const int*)d_in[3];
    const int*   graph_ids  = (const int*)d_in[4];
    const float* W1 = (const float*)d_in[5];
    const float* b1 = (const float*)d_in[6];
    const float* W2 = (const float*)d_in[7];
    const float* b2 = (const float*)d_in[8];
    const float* W3 = (const float*)d_in[9];
    const float* b3 = (const float*)d_in[10];
    const float* fcW1 = (const float*)d_in[11];
    const float* fcb1 = (const float*)d_in[12];
    const float* fcW2 = (const float*)d_in[13];
    const float* fcb2 = (const float*)d_in[14];
    const float* fcW3 = (const float*)d_in[15];
    const float* fcb3 = (const float*)d_in[16];
    const float* pW = (const float*)d_in[17];
    const float* pb = (const float*)d_in[18];
    float* out = (float*)d_out;

    // workspace carve-up (256B aligned)
    char* p = (char*)d_ws;
    auto alloc = [&](size_t bytes) -> void* {
        void* r = (void*)p;
        p += (bytes + 255) & ~(size_t)255;
        return r;
    };
    int* blk_hist  = (int*)alloc((size_t)SORT_BLOCKS * N_RELS * sizeof(int));
    int* blk_off   = (int*)alloc((size_t)SORT_BLOCKS * N_RELS * sizeof(int));
    int* rel_ptr   = (int*)alloc((N_RELS + 1) * sizeof(int));
    int* tile_base = (int*)alloc((N_RELS + 1) * sizeof(int));
    unsigned long long* epk = (unsigned long long*)alloc((size_t)N_EDGES * sizeof(unsigned long long));
    int* src_s     = (int*)alloc((size_t)N_EDGES * sizeof(int));
    int* dpos      = (int*)alloc((size_t)N_EDGES * sizeof(int));
    int* cnt_d     = (int*)alloc((size_t)N_NODES * sizeof(int));
    int* row_ptr   = (int*)alloc((size_t)N_NODES * sizeof(int));
    int* blk_tot   = (int*)alloc(NSCAN_BLKS * sizeof(int));
    int* blk_base  = (int*)alloc(NSCAN_BLKS * sizeof(int));
    int* cnt_g     = (int*)alloc(N_GRAPHS * sizeof(int));
    int* g_ptr     = (int*)alloc(N_GRAPHS * sizeof(int));
    __hip_bfloat16* hb0 = (__hip_bfloat16*)alloc((size_t)N_NODES * DIM * sizeof(__hip_bfloat16));
    __hip_bfloat16* hb1 = (__hip_bfloat16*)alloc((size_t)N_NODES * DIM * sizeof(__hip_bfloat16));
    __hip_bfloat16* Wt1 = (__hip_bfloat16*)alloc((size_t)N_RELS * DIM * DIM * sizeof(__hip_bfloat16));
    __hip_bfloat16* Wt2 = (__hip_bfloat16*)alloc((size_t)N_RELS * DIM * DIM * sizeof(__hip_bfloat16));
    __hip_bfloat16* Wt3 = (__hip_bfloat16*)alloc((size_t)N_RELS * DIM * DIM * sizeof(__hip_bfloat16));
    __hip_bfloat16* msg = (__hip_bfloat16*)alloc((size_t)N_EDGES * DIM * sizeof(__hip_bfloat16));

    const int EBLK = (N_EDGES + 255) / 256;              // 3125
    const int CBLK = (N_NODES * DIM / 4 + 255) / 256;    // 3125
    const int AGG_BLOCKS = (N_NODES + 3) / 4;            // 12500

    // ---- prep (8 dispatches) ----
    conv_h_zero_kernel<<<CBLK, 256, 0, stream>>>(node_feats, hb0, cnt_d, cnt_g);
    hist_all_kernel<<<SORT_BLOCKS, 256, 0, stream>>>(etypes, graph_ids, blk_hist, cnt_g,
                                                     W1, W2, W3, Wt1, Wt2, Wt3);
    relwave2_kernel<<<1, 1024, 0, stream>>>(blk_hist, blk_off, rel_ptr, tile_base);
    scatter2_kernel<<<SORT_BLOCKS, 256, 0, stream>>>(etypes, src, dst, blk_off, rel_ptr,
                                                     epk, cnt_d);
    scanblk_kernel<<<NSCAN_BLKS, SCAN_BLK, 0, stream>>>(cnt_d, row_ptr, blk_tot);
    scantop_gid_kernel<<<2, 64, 0, stream>>>(blk_tot, blk_base, cnt_g, g_ptr);
    scanadd_kernel<<<NSCAN_BLKS, SCAN_BLK, 0, stream>>>(row_ptr, blk_base);
    unpack_kernel<<<EBLK, 256, 0, stream>>>(epk, row_ptr, src_s, dpos);

    // ---- 3 RGCN layers (6 dispatches) ----
    msg_mfma_kernel<<<MSG_BLOCKS, 256, 0, stream>>>(hb0, Wt1, rel_ptr, tile_base,
                                                    src_s, dpos, msg);
    agg_kernel<<<AGG_BLOCKS, 256, 0, stream>>>(msg, row_ptr, cnt_d, b1, hb1);

    msg_mfma_kernel<<<MSG_BLOCKS, 256, 0, stream>>>(hb1, Wt2, rel_ptr, tile_base,
                                                    src_s, dpos, msg);
    agg_kernel<<<AGG_BLOCKS, 256, 0, stream>>>(msg, row_ptr, cnt_d, b2, hb0);

    msg_mfma_kernel<<<MSG_BLOCKS, 256, 0, stream>>>(hb0, Wt3, rel_ptr, tile_base,
                                                    src_s, dpos, msg);
    agg_kernel<<<AGG_BLOCKS, 256, 0, stream>>>(msg, row_ptr, cnt_d, b3, hb1);

    // ---- fused pool + FC head ----
    poolfc_kernel<<<(N_GRAPHS + 3) / 4, 256, 0, stream>>>(hb1, g_ptr, cnt_g,
                                                          fcW1, fcb1, fcW2, fcb2,
                                                          fcW3, fcb3, pW, pb, out);
}